// Round 2
// baseline (819.541 us; speedup 1.0000x reference)
//
#include <hip/hip_runtime.h>
#include <hip/hip_bf16.h>
#include <stdint.h>

// Problem constants: x[8192,4096] f32, qw[4096,4096] f32 in {-1,+1}, bias[4096]
#define B_DIM   8192
#define IN_DIM  4096
#define OUT_DIM 4096
#define QB_V    128.0f
#define EPS_V   1e-5f
// out-group: 512 rows  = 2^21 elems ; batch-group: 1024 rows = 2^22 elems

typedef __attribute__((ext_vector_type(4))) float  f32x4;
typedef __attribute__((ext_vector_type(8))) __bf16 bf16x8;
typedef __attribute__((ext_vector_type(4))) __bf16 bf16x4;

__device__ __forceinline__ void gload_lds16(const void* g, void* l) {
  void* gp = const_cast<void*>(g);
  __builtin_amdgcn_global_load_lds(
      (__attribute__((address_space(1))) void*)gp,
      (__attribute__((address_space(3))) void*)l, 16, 0, 0);
}

__device__ __forceinline__ __bf16 sgnb(float d) {
  return (__bf16)((d > 0.f) ? 1.f : (d < 0.f ? -1.f : 0.f));
}

// ---- zero the 16-word scratch header (sums[8] f32 + gamma_bits[8] u32) ----
__global__ void k_init(unsigned* ws) {
  int t = threadIdx.x;
  if (t < 16) ws[t] = 0u;
}

// ---- per-out-group sum of |qw| (integers -> exact f32 atomics) ----
__global__ __launch_bounds__(256) void k_qw_sums(const float* __restrict__ qw,
                                                 float* __restrict__ sums) {
  __shared__ float red[4];
  const int t = threadIdx.x;
  const size_t base = (size_t)blockIdx.x * 4096;
  float s = 0.f;
#pragma unroll
  for (int j = 0; j < 4; ++j) {
    f32x4 v = *(const f32x4*)(qw + base + (size_t)j * 1024 + t * 4);
    s += fabsf(v.x) + fabsf(v.y) + fabsf(v.z) + fabsf(v.w);
  }
#pragma unroll
  for (int off = 32; off > 0; off >>= 1) s += __shfl_xor(s, off);
  if ((t & 63) == 0) red[t >> 6] = s;
  __syncthreads();
  if (t == 0) {
    float bs = red[0] + red[1] + red[2] + red[3];
    atomicAdd(sums + (blockIdx.x >> 9), bs);  // 512 blocks per group
  }
}

// ---- bw = sign(qw - mu_g) as bf16, 16 elems/thread ----
__global__ __launch_bounds__(256) void k_conv_bw(const float* __restrict__ qw,
                                                 const float* __restrict__ sums,
                                                 __bf16* __restrict__ bw) {
  const size_t i = ((size_t)blockIdx.x * 256 + threadIdx.x) * 16;
  const int g = (int)(i >> 21);
  const float mu = sums[g] * (1.0f / 2097152.0f);  // / (512*4096)
#pragma unroll
  for (int h = 0; h < 2; ++h) {
    f32x4 v0 = *(const f32x4*)(qw + i + h * 8);
    f32x4 v1 = *(const f32x4*)(qw + i + h * 8 + 4);
    bf16x8 r;
    r[0] = sgnb(v0.x - mu); r[1] = sgnb(v0.y - mu);
    r[2] = sgnb(v0.z - mu); r[3] = sgnb(v0.w - mu);
    r[4] = sgnb(v1.x - mu); r[5] = sgnb(v1.y - mu);
    r[6] = sgnb(v1.z - mu); r[7] = sgnb(v1.w - mu);
    *(bf16x8*)(bw + i + h * 8) = r;
  }
}

// ---- x -> bf16, 16 elems/thread ----
__global__ __launch_bounds__(256) void k_conv_x(const float* __restrict__ x,
                                                __bf16* __restrict__ xb) {
  const size_t i = ((size_t)blockIdx.x * 256 + threadIdx.x) * 16;
#pragma unroll
  for (int h = 0; h < 2; ++h) {
    f32x4 v0 = *(const f32x4*)(x + i + h * 8);
    f32x4 v1 = *(const f32x4*)(x + i + h * 8 + 4);
    bf16x8 r;
    r[0] = (__bf16)v0.x; r[1] = (__bf16)v0.y;
    r[2] = (__bf16)v0.z; r[3] = (__bf16)v0.w;
    r[4] = (__bf16)v1.x; r[5] = (__bf16)v1.y;
    r[6] = (__bf16)v1.z; r[7] = (__bf16)v1.w;
    *(bf16x8*)(xb + i + h * 8) = r;
  }
}

// ---- GEMM: out[b,o] = sum_k x[b,k]*bw[o,k] + bias[o]; fused group-|max| ----
// 128x128 tile, BK=64, 256 thr = 4 waves (2x2), 64x64/wave, 16x16x32 bf16 MFMA.
// LDS tiles [row][64] bf16 with XOR chunk-swizzle: 16B chunk c of row r holds
// global chunk c ^ (r&7). Staged via global_load_lds (linear dest) with the
// inverse permutation applied to the per-lane GLOBAL source (rule 21).
// AMODE 0: A,B pre-converted bf16 (needs 96MB ws)
// AMODE 1: A reg-staged from f32 x; B pre-converted (needs 32MB ws)
// AMODE 2: A and B reg-staged from f32 (ws header only)
template <int AMODE>
__global__ __launch_bounds__(256) void k_gemm(
    const __bf16* __restrict__ xa, const float* __restrict__ xf,
    const __bf16* __restrict__ bwb, const float* __restrict__ qw,
    const float* __restrict__ sums, const float* __restrict__ bias,
    float* __restrict__ out, unsigned* __restrict__ gamma_bits) {
  __shared__ __bf16 As[128 * 64];
  __shared__ __bf16 Bs[128 * 64];
  const int t = threadIdx.x;
  const int lane = t & 63;
  const int wv = t >> 6;
  const int wr = wv >> 1, wc = wv & 1;
  const int fr = lane & 15, fq = lane >> 4;
  const int fr7 = fr & 7;
  // XCD-aware bijective swizzle (grid == 2048, 2048 % 8 == 0)
  const int orig = blockIdx.x;
  const int bid = ((orig & 7) << 8) | (orig >> 3);
  const int bm = bid & 63, bn = bid >> 6;
  const int brow = bm << 7, bcol = bn << 7;

  f32x4 acc[4][4] = {};

  // staging: thread t covers (row = t>>3 [+32/it], chunk = t&7); source chunk
  // is swizzled by row&7 so a linear-dest global_load_lds lands swizzled.
  const int c0row = t >> 3;                      // +32 per it
  const int cchunk = t & 7;
  const int schunk = cchunk ^ (c0row & 7);       // (t>>3)&7, invariant per it
  const int ccol = cchunk << 3;                  // LDS elem col (dest, linear)
  const int scol = schunk << 3;                  // global elem col (source)

  float muB = 0.f;
  if (AMODE == 2) muB = sums[bcol >> 9] * (1.0f / 2097152.0f);

  for (int kt = 0; kt < IN_DIM / 64; ++kt) {
    const int k0 = kt << 6;
    if (AMODE == 0) {
      __syncthreads();
#pragma unroll
      for (int it = 0; it < 4; ++it) {
        const int row = c0row + it * 32;
        gload_lds16(xa + (size_t)(brow + row) * IN_DIM + k0 + scol,
                    As + (row << 6) + ccol);
        gload_lds16(bwb + (size_t)(bcol + row) * IN_DIM + k0 + scol,
                    Bs + (row << 6) + ccol);
      }
      __syncthreads();
    } else if (AMODE == 1) {
      f32x4 a0[4], a1[4];
#pragma unroll
      for (int it = 0; it < 4; ++it) {
        const int row = c0row + it * 32;
        const float* p = xf + (size_t)(brow + row) * IN_DIM + k0 + scol;
        a0[it] = *(const f32x4*)p;
        a1[it] = *(const f32x4*)(p + 4);
      }
      __syncthreads();
#pragma unroll
      for (int it = 0; it < 4; ++it) {
        const int row = c0row + it * 32;
        gload_lds16(bwb + (size_t)(bcol + row) * IN_DIM + k0 + scol,
                    Bs + (row << 6) + ccol);
      }
#pragma unroll
      for (int it = 0; it < 4; ++it) {
        const int row = c0row + it * 32;
        bf16x8 w;
        w[0] = (__bf16)a0[it].x; w[1] = (__bf16)a0[it].y;
        w[2] = (__bf16)a0[it].z; w[3] = (__bf16)a0[it].w;
        w[4] = (__bf16)a1[it].x; w[5] = (__bf16)a1[it].y;
        w[6] = (__bf16)a1[it].z; w[7] = (__bf16)a1[it].w;
        // reg->LDS write: swizzle the DEST (content is source chunk `schunk`);
        // schunk ^ (row&7) == cchunk, so dest col is ccol. Linear == swizzled.
        *(bf16x8*)(As + (row << 6) + ccol) = w;
      }
      __syncthreads();
    } else {
      f32x4 a0[4], a1[4], b0[4], b1[4];
#pragma unroll
      for (int it = 0; it < 4; ++it) {
        const int row = c0row + it * 32;
        const float* pa = xf + (size_t)(brow + row) * IN_DIM + k0 + scol;
        a0[it] = *(const f32x4*)pa;
        a1[it] = *(const f32x4*)(pa + 4);
        const float* pb = qw + (size_t)(bcol + row) * IN_DIM + k0 + scol;
        b0[it] = *(const f32x4*)pb;
        b1[it] = *(const f32x4*)(pb + 4);
      }
      __syncthreads();
#pragma unroll
      for (int it = 0; it < 4; ++it) {
        const int row = c0row + it * 32;
        bf16x8 wa, wb;
        wa[0] = (__bf16)a0[it].x; wa[1] = (__bf16)a0[it].y;
        wa[2] = (__bf16)a0[it].z; wa[3] = (__bf16)a0[it].w;
        wa[4] = (__bf16)a1[it].x; wa[5] = (__bf16)a1[it].y;
        wa[6] = (__bf16)a1[it].z; wa[7] = (__bf16)a1[it].w;
        wb[0] = sgnb(b0[it].x - muB); wb[1] = sgnb(b0[it].y - muB);
        wb[2] = sgnb(b0[it].z - muB); wb[3] = sgnb(b0[it].w - muB);
        wb[4] = sgnb(b1[it].x - muB); wb[5] = sgnb(b1[it].y - muB);
        wb[6] = sgnb(b1[it].z - muB); wb[7] = sgnb(b1[it].w - muB);
        *(bf16x8*)(As + (row << 6) + ccol) = wa;
        *(bf16x8*)(Bs + (row << 6) + ccol) = wb;
      }
      __syncthreads();
    }

    // 2 K-steps of 32 -> 32 MFMAs per barrier pair.
    // Fragment read of row r, chunk q is at swizzled chunk q ^ (r&7):
    // 64 lanes spread 8-per-chunk across all 8 chunks = conflict-free minimum.
#pragma unroll
    for (int ks = 0; ks < 2; ++ks) {
      bf16x8 af[4], bfr[4];
#pragma unroll
      for (int mi = 0; mi < 4; ++mi)
        af[mi] = *(const bf16x8*)(As + (((wr << 6) + (mi << 4) + fr) << 6) +
                                  ((((ks << 2) | fq) ^ fr7) << 3));
#pragma unroll
      for (int ni = 0; ni < 4; ++ni)
        bfr[ni] = *(const bf16x8*)(Bs + (((wc << 6) + (ni << 4) + fr) << 6) +
                                   ((((ks << 2) | fq) ^ fr7) << 3));
#pragma unroll
      for (int mi = 0; mi < 4; ++mi)
#pragma unroll
        for (int ni = 0; ni < 4; ++ni)
          acc[mi][ni] = __builtin_amdgcn_mfma_f32_16x16x32_bf16(
              af[mi], bfr[ni], acc[mi][ni], 0, 0, 0);
    }
  }

  // epilogue: +bias, store f32, fused per-batch-group abs-max
  float mx = 0.f;
  const int colbase = bcol + (wc << 6);
#pragma unroll
  for (int ni = 0; ni < 4; ++ni) {
    const int col = colbase + (ni << 4) + fr;
    const float bv = bias[col];
#pragma unroll
    for (int mi = 0; mi < 4; ++mi) {
      const int rowb = brow + (wr << 6) + (mi << 4) + (fq << 2);
#pragma unroll
      for (int j = 0; j < 4; ++j) {
        const float v = acc[mi][ni][j] + bv;
        out[(size_t)(rowb + j) * OUT_DIM + col] = v;
        mx = fmaxf(mx, fabsf(v));
      }
    }
  }
#pragma unroll
  for (int off = 32; off > 0; off >>= 1) mx = fmaxf(mx, __shfl_xor(mx, off));
  if (lane == 0)
    atomicMax(gamma_bits + (brow >> 10), __float_as_uint(mx));
}

// ---- q = clip(out * 128/(gamma_g+eps), -128+eps, 128-eps), 16 elems/thr ----
__global__ __launch_bounds__(256) void k_scale(float* __restrict__ out,
                                               const unsigned* __restrict__ gb) {
  const size_t i = ((size_t)blockIdx.x * 256 + threadIdx.x) * 16;
  const int g = (int)(i >> 22);
  const float gamma = __uint_as_float(gb[g]);
  const float sc = QB_V / (gamma + EPS_V);
  const float lo = -QB_V + EPS_V, hi = QB_V - EPS_V;
#pragma unroll
  for (int h = 0; h < 4; ++h) {
    f32x4 v = *(const f32x4*)(out + i + h * 4);
    v.x = fminf(fmaxf(v.x * sc, lo), hi);
    v.y = fminf(fmaxf(v.y * sc, lo), hi);
    v.z = fminf(fmaxf(v.z * sc, lo), hi);
    v.w = fminf(fmaxf(v.w * sc, lo), hi);
    *(f32x4*)(out + i + h * 4) = v;
  }
}

extern "C" void kernel_launch(void* const* d_in, const int* in_sizes, int n_in,
                              void* d_out, int out_size, void* d_ws,
                              size_t ws_size, hipStream_t stream) {
  const float* x = (const float*)d_in[0];
  const float* qw = (const float*)d_in[1];
  const float* bias = (const float*)d_in[2];
  float* out = (float*)d_out;
  char* ws = (char*)d_ws;
  float* sums = (float*)ws;                   // 8 x f32
  unsigned* gamma = (unsigned*)ws + 8;        // 8 x u32 (f32 bits, >=0)
  __bf16* bwb = (__bf16*)(ws + 256);
  __bf16* xb = (__bf16*)(ws + 256 + (size_t)OUT_DIM * IN_DIM * 2);

  const size_t need1 = 256 + (size_t)OUT_DIM * IN_DIM * 2;                 // 32MB
  const size_t need0 = need1 + (size_t)B_DIM * IN_DIM * 2;                 // +64MB
  const int amode = (ws_size >= need0) ? 0 : ((ws_size >= need1) ? 1 : 2);

  k_init<<<1, 64, 0, stream>>>((unsigned*)ws);
  k_qw_sums<<<4096, 256, 0, stream>>>(qw, sums);
  if (amode <= 1) k_conv_bw<<<4096, 256, 0, stream>>>(qw, sums, bwb);
  if (amode == 0) k_conv_x<<<8192, 256, 0, stream>>>(x, xb);

  if (amode == 0)
    k_gemm<0><<<2048, 256, 0, stream>>>(xb, x, bwb, qw, sums, bias, out, gamma);
  else if (amode == 1)
    k_gemm<1><<<2048, 256, 0, stream>>>(xb, x, bwb, qw, sums, bias, out, gamma);
  else
    k_gemm<2><<<2048, 256, 0, stream>>>(xb, x, bwb, qw, sums, bias, out, gamma);

  k_scale<<<8192, 256, 0, stream>>>(out, gamma);
}

// Round 3
// 701.177 us; speedup vs baseline: 1.1688x; 1.1688x over previous
//
#include <hip/hip_runtime.h>
#include <hip/hip_bf16.h>
#include <stdint.h>

// x[8192,4096] f32, qw[4096,4096] f32 in {-1,+1}, bias[4096] f32
#define B_DIM   8192
#define IN_DIM  4096
#define OUT_DIM 4096
#define QB_V    128.0f
#define EPS_V   1e-5f
// out-group: 512 rows = 2^21 elems ; batch-group: 1024 rows = 2^22 elems

typedef __attribute__((ext_vector_type(4))) float  f32x4;
typedef __attribute__((ext_vector_type(8))) __bf16 bf16x8;

__device__ __forceinline__ void gload_lds16(const void* g, void* l) {
  void* gp = const_cast<void*>(g);
  __builtin_amdgcn_global_load_lds(
      (__attribute__((address_space(1))) void*)gp,
      (__attribute__((address_space(3))) void*)l, 16, 0, 0);
}

__device__ __forceinline__ __bf16 sgnb(float d) {
  return (__bf16)((d > 0.f) ? 1.f : (d < 0.f ? -1.f : 0.f));
}

// ---- zero scratch header: sums[8] f32 + gamma_bits[8] u32 ----
__global__ void k_init(unsigned* ws) {
  int t = threadIdx.x;
  if (t < 16) ws[t] = 0u;
}

// ---- per-out-group sum of |qw| (integer-valued -> exact f32 atomics) ----
__global__ __launch_bounds__(256) void k_qw_sums(const float* __restrict__ qw,
                                                 float* __restrict__ sums) {
  __shared__ float red[4];
  const int t = threadIdx.x;
  for (int vb = blockIdx.x; vb < 4096; vb += 2048) {
    const size_t base = (size_t)vb * 4096;
    float s = 0.f;
#pragma unroll
    for (int j = 0; j < 4; ++j) {
      f32x4 v = *(const f32x4*)(qw + base + (size_t)j * 1024 + t * 4);
      s += fabsf(v.x) + fabsf(v.y) + fabsf(v.z) + fabsf(v.w);
    }
#pragma unroll
    for (int off = 32; off > 0; off >>= 1) s += __shfl_xor(s, off);
    __syncthreads();
    if ((t & 63) == 0) red[t >> 6] = s;
    __syncthreads();
    if (t == 0)
      atomicAdd(sums + (vb >> 9), red[0] + red[1] + red[2] + red[3]);
  }
}

// ---- merged: bw = sign(qw - mu_g) bf16 (vb 0..4095) ; x -> bf16 (vb 4096..12287) ----
__global__ __launch_bounds__(256) void k_conv(const float* __restrict__ qw,
                                              const float* __restrict__ sums,
                                              __bf16* __restrict__ bw,
                                              const float* __restrict__ x,
                                              __bf16* __restrict__ xb) {
  const int t = threadIdx.x;
  for (int vb = blockIdx.x; vb < 12288; vb += 2048) {
    if (vb < 4096) {
      const size_t i = ((size_t)vb * 256 + t) * 16;
      const float mu = sums[(int)(i >> 21)] * (1.0f / 2097152.0f);
#pragma unroll
      for (int h = 0; h < 2; ++h) {
        f32x4 v0 = *(const f32x4*)(qw + i + h * 8);
        f32x4 v1 = *(const f32x4*)(qw + i + h * 8 + 4);
        bf16x8 r;
        r[0] = sgnb(v0.x - mu); r[1] = sgnb(v0.y - mu);
        r[2] = sgnb(v0.z - mu); r[3] = sgnb(v0.w - mu);
        r[4] = sgnb(v1.x - mu); r[5] = sgnb(v1.y - mu);
        r[6] = sgnb(v1.z - mu); r[7] = sgnb(v1.w - mu);
        *(bf16x8*)(bw + i + h * 8) = r;
      }
    } else {
      const size_t i = ((size_t)(vb - 4096) * 256 + t) * 16;
#pragma unroll
      for (int h = 0; h < 2; ++h) {
        f32x4 v0 = *(const f32x4*)(x + i + h * 8);
        f32x4 v1 = *(const f32x4*)(x + i + h * 8 + 4);
        bf16x8 r;
        r[0] = (__bf16)v0.x; r[1] = (__bf16)v0.y;
        r[2] = (__bf16)v0.z; r[3] = (__bf16)v0.w;
        r[4] = (__bf16)v1.x; r[5] = (__bf16)v1.y;
        r[6] = (__bf16)v1.z; r[7] = (__bf16)v1.w;
        *(bf16x8*)(xb + i + h * 8) = r;
      }
    }
  }
}

// ---- GEMM 256x256 tile, BK=64, 512 thr = 8 waves (2x4), 128x64/wave ----
// Double-buffered LDS (128 KB), T2 XOR chunk-swizzle, counted vmcnt pipeline:
//   tile t start: [B1] issue A(t+1)->buf[d^1]; s_waitcnt vmcnt(4); [B2]
//   phase ks=0: ds_read frags(buf[d]) -> 32 MFMA ; issue B(t+1)->buf[d^1]
//   phase ks=1: ds_read frags(buf[d]) -> 32 MFMA
// Next-tile loads stay in flight across both barriers (T4); vmcnt(0) only on
// the last tile. Raw s_barrier (no implicit vmcnt drain), setprio on MFMA (T5).
__global__ __launch_bounds__(512, 2) void k_gemm256(
    const __bf16* __restrict__ xa, const __bf16* __restrict__ bwb,
    const float* __restrict__ bias, float* __restrict__ out,
    unsigned* __restrict__ gamma_bits) {
  __shared__ __bf16 As[2][256 * 64];
  __shared__ __bf16 Bs[2][256 * 64];
  const int t = threadIdx.x;
  const int lane = t & 63;
  const int wv = t >> 6;          // 0..7
  const int wr = wv >> 2;         // 0..1 (M half)
  const int wc = wv & 3;          // 0..3 (N quarter)
  const int fr = lane & 15, fq = lane >> 4;
  const int fr7 = fr & 7;

  // XCD-aware bijective swizzle: grid=512, 512%8==0, chunk=64
  const int orig = blockIdx.x;
  const int bid = ((orig & 7) << 6) | (orig >> 3);
  const int bm = bid & 31, bn = bid >> 5;
  const int brow = bm << 8, bcol = bn << 8;

  // staging: thread t covers (row = t>>3 [+64/round], chunk = t&7)
  // T2: LDS chunk c of row r holds global chunk c ^ (r&7); dest linear in t
  // (wave-uniform base + lane*16 as global_load_lds requires).
  const int srow = t >> 3;
  const int cchunk = t & 7;
  const int schunk = cchunk ^ (srow & 7);
  const int dstoff = (srow << 6) + (cchunk << 3);   // elems
  const __bf16* aRow = xa + (size_t)(brow + srow) * IN_DIM + (schunk << 3);
  const __bf16* bRow = bwb + (size_t)(bcol + srow) * IN_DIM + (schunk << 3);

#define STAGE_A(kt, dd)                                                     \
  {                                                                         \
    const int _k0 = (kt) << 6;                                              \
    _Pragma("unroll") for (int r = 0; r < 4; ++r)                           \
        gload_lds16(aRow + (size_t)(r << 6) * IN_DIM + _k0,                 \
                    &As[dd][(r << 12) + dstoff]);                           \
  }
#define STAGE_B(kt, dd)                                                     \
  {                                                                         \
    const int _k0 = (kt) << 6;                                              \
    _Pragma("unroll") for (int r = 0; r < 4; ++r)                           \
        gload_lds16(bRow + (size_t)(r << 6) * IN_DIM + _k0,                 \
                    &Bs[dd][(r << 12) + dstoff]);                           \
  }

  f32x4 acc[8][4] = {};

  // prologue: tile 0 fully staged into buf 0
  STAGE_A(0, 0);
  STAGE_B(0, 0);

  int d = 0;
  for (int kt = 0; kt < 64; ++kt) {
    __builtin_amdgcn_s_barrier();               // closes tile t-1 reads
    if (kt < 63) {
      STAGE_A(kt + 1, d ^ 1);
      asm volatile("s_waitcnt vmcnt(4)" ::: "memory");  // tile t landed; A(t+1) in flight
    } else {
      asm volatile("s_waitcnt vmcnt(0)" ::: "memory");
    }
    __builtin_amdgcn_s_barrier();               // tile t visible to all waves

#pragma unroll
    for (int ks = 0; ks < 2; ++ks) {
      const int cs = (ks << 2) | fq;
      bf16x8 af[8], bfv[4];
#pragma unroll
      for (int m = 0; m < 8; ++m)
        af[m] = *(const bf16x8*)(&As[d][(((wr << 7) + (m << 4) + fr) << 6) +
                                        ((cs ^ fr7) << 3)]);
#pragma unroll
      for (int n = 0; n < 4; ++n)
        bfv[n] = *(const bf16x8*)(&Bs[d][(((wc << 6) + (n << 4) + fr) << 6) +
                                         ((cs ^ fr7) << 3)]);
      __builtin_amdgcn_s_setprio(1);
#pragma unroll
      for (int m = 0; m < 8; ++m)
#pragma unroll
        for (int n = 0; n < 4; ++n)
          acc[m][n] = __builtin_amdgcn_mfma_f32_16x16x32_bf16(
              af[m], bfv[n], acc[m][n], 0, 0, 0);
      __builtin_amdgcn_s_setprio(0);
      if (ks == 0 && kt < 63) STAGE_B(kt + 1, d ^ 1);
    }
    d ^= 1;
  }
#undef STAGE_A
#undef STAGE_B

  // epilogue: +bias, store f32, fused per-batch-group abs-max
  float mx = 0.f;
  const int colbase = bcol + (wc << 6);
#pragma unroll
  for (int n = 0; n < 4; ++n) {
    const int col = colbase + (n << 4) + fr;
    const float bv = bias[col];
#pragma unroll
    for (int m = 0; m < 8; ++m) {
      const int rowb = brow + (wr << 7) + (m << 4) + (fq << 2);
#pragma unroll
      for (int j = 0; j < 4; ++j) {
        const float v = acc[m][n][j] + bv;
        out[(size_t)(rowb + j) * OUT_DIM + col] = v;
        mx = fmaxf(mx, fabsf(v));
      }
    }
  }
#pragma unroll
  for (int off = 32; off > 0; off >>= 1) mx = fmaxf(mx, __shfl_xor(mx, off));
  if (lane == 0)
    atomicMax(gamma_bits + (brow >> 10), __float_as_uint(mx));
}

// ---- q = clip(out * 128/(gamma_g+eps), -128+eps, 128-eps), in place ----
__global__ __launch_bounds__(256) void k_scale(float* __restrict__ out,
                                               const unsigned* __restrict__ gb) {
  const int t = threadIdx.x;
  for (int vb = blockIdx.x; vb < 8192; vb += 2048) {
    const size_t i = ((size_t)vb * 256 + t) * 16;
    const float gamma = __uint_as_float(gb[(int)(i >> 22)]);
    const float sc = QB_V / (gamma + EPS_V);
    const float lo = -QB_V + EPS_V, hi = QB_V - EPS_V;
#pragma unroll
    for (int h = 0; h < 4; ++h) {
      f32x4 v = *(const f32x4*)(out + i + h * 4);
      v.x = fminf(fmaxf(v.x * sc, lo), hi);
      v.y = fminf(fmaxf(v.y * sc, lo), hi);
      v.z = fminf(fmaxf(v.z * sc, lo), hi);
      v.w = fminf(fmaxf(v.w * sc, lo), hi);
      *(f32x4*)(out + i + h * 4) = v;
    }
  }
}

extern "C" void kernel_launch(void* const* d_in, const int* in_sizes, int n_in,
                              void* d_out, int out_size, void* d_ws,
                              size_t ws_size, hipStream_t stream) {
  const float* x = (const float*)d_in[0];
  const float* qw = (const float*)d_in[1];
  const float* bias = (const float*)d_in[2];
  float* out = (float*)d_out;
  char* ws = (char*)d_ws;
  float* sums = (float*)ws;                    // 8 x f32
  unsigned* gamma = (unsigned*)ws + 8;         // 8 x u32 (f32 bits, >=0)
  __bf16* bwb = (__bf16*)(ws + 256);                                   // 32 MB
  __bf16* xb = (__bf16*)(ws + 256 + (size_t)OUT_DIM * IN_DIM * 2);     // 64 MB

  k_init<<<1, 64, 0, stream>>>((unsigned*)ws);
  k_qw_sums<<<2048, 256, 0, stream>>>(qw, sums);
  k_conv<<<2048, 256, 0, stream>>>(qw, sums, bwb, x, xb);
  k_gemm256<<<512, 512, 0, stream>>>(xb, bwb, bias, out, gamma);
  k_scale<<<2048, 256, 0, stream>>>(out, gamma);
}